// Round 5
// baseline (165.806 us; speedup 1.0000x reference)
//
#include <hip/hip_runtime.h>

// SoftAttentionAlignment B=8, L=2048, D=128 fp32. MFMA flash attention, both dirs.
// R10: R7's HARNESS-VERIFIED dataflow (K row-major f16; V d-major bf16, stride-72
//      + 64B bit3-swizzle, scalar-scatter writes; ds_read_b128 fragments;
//      in-register P via cvt_pk+permlane) with ONE structural change:
//      32 q-rows per wave (row-blocks rb=0,1 share ALL K/V fragment reads).
//      Per-group-tile LDS traffic 80KB -> 48KB (-40%); R7 PMC showed the LDS pipe
//      (volume + conflicts) was ~53% of the wall. Block 256 = 2 j-groups x 2 waves;
//      grid 512 (2 blocks/CU, 8 waves/CU). tr_read abandoned (2 failed rounds,
//      unresolvable semantics from here).

typedef __bf16    bf16;
typedef _Float16  f16;
typedef __bf16    bf16x8 __attribute__((ext_vector_type(8)));
typedef _Float16  f16x8  __attribute__((ext_vector_type(8)));
typedef float     floatx4 __attribute__((ext_vector_type(4)));
typedef unsigned int uintx4 __attribute__((ext_vector_type(4)));

#define NB 8
#define SL 2048
#define TI 64
#define NT 32            // 32 j-tiles of 32 per group (group owns 1024 j)

#define SKV_S  136   // f16 elems per j-row (272 B = 17*16: uniform bank slots)
#define SVT_S  72    // bf16 elems per d-row (144 B = 9*16) + 32-elem swizzle on d bit3

// per-group LDS: sKV [32][136] f16 = 8704 B ; sVT [128][72] bf16 = 18432 B
#define GSPAN    27136
#define OFF_VT   8704
#define OFF_L    54272           // float[64]
#define LDS_BYTES 54528          // aOut fp32 [64][132] = 33792 overlaps group buffers

__global__ __launch_bounds__(256, 2)
void soft_attn_align_mfma(const float* __restrict__ x1,
                          const float* __restrict__ x2,
                          float* __restrict__ out)
{
    __shared__ __align__(16) char lds_raw[LDS_BYTES];

    const int tid  = threadIdx.x;
    const int lane = tid & 63;
    const int wv   = tid >> 6;          // 0..3
    const int g    = wv >> 1;           // j-half group
    const int rowbase = (wv & 1) * 32;  // wave's 32 q-rows within the 64-row tile
    const int lr   = lane & 15;
    const int lq   = lane >> 4;
    const int t128 = tid & 127;         // thread id within group

    char* gb   = lds_raw + g * GSPAN;
    f16*   sKV  = (f16*) (gb);             // [32][136] fp16 row-major (j, d)
    bf16*  sVT  = (bf16*)(gb + OFF_VT);    // [128][72] bf16 d-major (d, j), swizzled
    float* aOut = (float*)(lds_raw);       // [64][132] fp32 (epilogue/combine)
    float* sL   = (float*)(lds_raw + OFF_L);

    const int i0  = blockIdx.x * TI;
    const int bi  = blockIdx.y;
    const int dir = blockIdx.z;

    const float* xq  = dir ? x2 : x1;
    const float* xkv = dir ? x1 : x2;

    // ---- Q fragments (fp16) into registers, once: 2 row-blocks x 4 ksteps ----
    f16x8 aQ[2][4];
    #pragma unroll
    for (int rb = 0; rb < 2; ++rb) {
        const float* qrow = xq + ((size_t)bi * SL + i0 + rowbase + rb * 16 + lr) * 128;
        #pragma unroll
        for (int kk = 0; kk < 4; ++kk) {
            const float4* src = (const float4*)(qrow + kk * 32 + lq * 8);
            float4 va = src[0], vb = src[1];
            float v[8] = {va.x, va.y, va.z, va.w, vb.x, vb.y, vb.z, vb.w};
            f16x8 f;
            #pragma unroll
            for (int i = 0; i < 8; ++i) f[i] = (f16)v[i];
            aQ[rb][kk] = f;
        }
    }

    float   l_acc[2] = {0.f, 0.f};
    floatx4 Oacc[2][8];
    #pragma unroll
    for (int rb = 0; rb < 2; ++rb)
        #pragma unroll
        for (int nd = 0; nd < 8; ++nd) Oacc[rb][nd] = (floatx4){0.f, 0.f, 0.f, 0.f};

    // staging: thread covers row r_st, col-chunks cp = c0 + 4k (k=0..3)
    const int r_st = t128 & 31;
    const int c0   = t128 >> 5;          // 0..3
    const float* kvbase = xkv + ((size_t)bi * SL + g * 1024 + r_st) * 128;

    float4 ld[4][2];
    {   // prologue: load tile 0
        #pragma unroll
        for (int k = 0; k < 4; ++k) {
            const float4* s = (const float4*)(kvbase + (c0 + 4 * k) * 8);
            ld[k][0] = s[0]; ld[k][1] = s[1];
        }
    }

    for (int t = 0; t < NT; ++t) {
        __syncthreads();   // (A) prev tile's fragment reads done before restage

        // ---- convert + write staged regs (tile t) ----
        #pragma unroll
        for (int k = 0; k < 4; ++k) {
            const int cp = c0 + 4 * k;          // parity of cp == parity of c0
            float4 va = ld[k][0], vb = ld[k][1];
            float v[8] = {va.x, va.y, va.z, va.w, vb.x, vb.y, vb.z, vb.w};
            f16x8 fh;
            #pragma unroll
            for (int i = 0; i < 8; ++i) fh[i] = (f16)v[i];
            *(f16x8*)(sKV + r_st * SKV_S + cp * 8) = fh;
            const int vbase = cp * 8 * SVT_S + r_st + 32 * (cp & 1);
            #pragma unroll
            for (int i = 0; i < 8; ++i)
                sVT[vbase + i * SVT_S] = (bf16)v[i];
        }
        __syncthreads();   // (B) tile t staged

        // ---- issue global loads for tile t+1 (land under the MFMA work) ----
        if (t < NT - 1) {
            const float* kb = kvbase + (size_t)(t + 1) * 32 * 128;
            #pragma unroll
            for (int k = 0; k < 4; ++k) {
                const float4* s = (const float4*)(kb + (c0 + 4 * k) * 8);
                ld[k][0] = s[0]; ld[k][1] = s[1];
            }
        }

        // ---- S^T = K . Q^T : lane holds S[i=rowbase+16rb+lr][j = 16n+4lq+r] ----
        floatx4 Sf[2][2];
        Sf[0][0] = (floatx4){0.f,0.f,0.f,0.f}; Sf[0][1] = (floatx4){0.f,0.f,0.f,0.f};
        Sf[1][0] = (floatx4){0.f,0.f,0.f,0.f}; Sf[1][1] = (floatx4){0.f,0.f,0.f,0.f};
        __builtin_amdgcn_s_setprio(1);
        #pragma unroll
        for (int kk = 0; kk < 4; ++kk) {
            f16x8 aK0 = *(const f16x8*)(sKV + (lr)      * SKV_S + kk * 32 + lq * 8);
            f16x8 aK1 = *(const f16x8*)(sKV + (16 + lr) * SKV_S + kk * 32 + lq * 8);
            Sf[0][0] = __builtin_amdgcn_mfma_f32_16x16x32_f16(aK0, aQ[0][kk], Sf[0][0], 0, 0, 0);
            Sf[0][1] = __builtin_amdgcn_mfma_f32_16x16x32_f16(aK1, aQ[0][kk], Sf[0][1], 0, 0, 0);
            Sf[1][0] = __builtin_amdgcn_mfma_f32_16x16x32_f16(aK0, aQ[1][kk], Sf[1][0], 0, 0, 0);
            Sf[1][1] = __builtin_amdgcn_mfma_f32_16x16x32_f16(aK1, aQ[1][kk], Sf[1][1], 0, 0, 0);
        }
        __builtin_amdgcn_s_setprio(0);

        // ---- p = exp(S); pack bf16; permlane-redistribute into PV A-frags ----
        bf16x8 aP[2];
        #pragma unroll
        for (int rb = 0; rb < 2; ++rb) {
            float p00 = __expf(Sf[rb][0][0]), p01 = __expf(Sf[rb][0][1]);
            float p02 = __expf(Sf[rb][0][2]), p03 = __expf(Sf[rb][0][3]);
            float p10 = __expf(Sf[rb][1][0]), p11 = __expf(Sf[rb][1][1]);
            float p12 = __expf(Sf[rb][1][2]), p13 = __expf(Sf[rb][1][3]);
            l_acc[rb] += ((p00 + p01) + (p02 + p03)) + ((p10 + p11) + (p12 + p13));

            unsigned int A0, B0, A1, B1;
            asm("v_cvt_pk_bf16_f32 %0, %1, %2" : "=v"(A0) : "v"(p00), "v"(p01));
            asm("v_cvt_pk_bf16_f32 %0, %1, %2" : "=v"(B0) : "v"(p02), "v"(p03));
            asm("v_cvt_pk_bf16_f32 %0, %1, %2" : "=v"(A1) : "v"(p10), "v"(p11));
            asm("v_cvt_pk_bf16_f32 %0, %1, %2" : "=v"(B1) : "v"(p12), "v"(p13));
            asm("v_permlane32_swap_b32 %0, %1" : "+v"(A0), "+v"(A1));
            asm("v_permlane16_swap_b32 %0, %1" : "+v"(A0), "+v"(A1));  // A0=d0, A1=d2
            asm("v_permlane32_swap_b32 %0, %1" : "+v"(B0), "+v"(B1));
            asm("v_permlane16_swap_b32 %0, %1" : "+v"(B0), "+v"(B1));  // B0=d1, B1=d3
            uintx4 fr; fr.x = A0; fr.y = B0; fr.z = A1; fr.w = B1;
            aP[rb] = __builtin_bit_cast(bf16x8, fr);
        }

        // ---- O += P . V  (V fragment read once, shared across both rb) ----
        const int voff = lq * 8 + 32 * ((lr >> 3) & 1);
        __builtin_amdgcn_s_setprio(1);
        #pragma unroll
        for (int nd = 0; nd < 8; ++nd) {
            bf16x8 bV = *(const bf16x8*)(sVT + (nd * 16 + lr) * SVT_S + voff);
            Oacc[0][nd] = __builtin_amdgcn_mfma_f32_16x16x32_bf16(aP[0], bV, Oacc[0][nd], 0, 0, 0);
            Oacc[1][nd] = __builtin_amdgcn_mfma_f32_16x16x32_bf16(aP[1], bV, Oacc[1][nd], 0, 0, 0);
        }
        __builtin_amdgcn_s_setprio(0);
    }

    // ---- row sums: lane holds partial for i = rowbase+16rb+lr; reduce over lq ----
    float l_row[2][4];
    #pragma unroll
    for (int rb = 0; rb < 2; ++rb) {
        float lv = l_acc[rb];
        lv += __shfl_xor(lv, 16, 64);
        lv += __shfl_xor(lv, 32, 64);
        #pragma unroll
        for (int r = 0; r < 4; ++r)
            l_row[rb][r] = __shfl(lv, lq * 4 + r, 64);
    }

    __syncthreads();   // all tile-buffer reads done before combine overwrites LDS

    // ---- combine j-halves: group 1 publishes partials, group 0 merges ----
    if (g == 1) {
        #pragma unroll
        for (int rb = 0; rb < 2; ++rb)
            #pragma unroll
            for (int r = 0; r < 4; ++r) {
                int row = rowbase + rb * 16 + lq * 4 + r;
                #pragma unroll
                for (int nd = 0; nd < 8; ++nd)
                    aOut[row * 132 + nd * 16 + lr] = Oacc[rb][nd][r];
                if (lr == 0) sL[row] = l_row[rb][r];
            }
    }
    __syncthreads();
    if (g == 0) {
        #pragma unroll
        for (int rb = 0; rb < 2; ++rb)
            #pragma unroll
            for (int r = 0; r < 4; ++r) {
                int row = rowbase + rb * 16 + lq * 4 + r;
                float inv = 1.0f / (l_row[rb][r] + sL[row]);
                #pragma unroll
                for (int nd = 0; nd < 8; ++nd) {
                    int idx = row * 132 + nd * 16 + lr;
                    aOut[idx] = (Oacc[rb][nd][r] + aOut[idx]) * inv;
                }
            }
    }
    __syncthreads();

    // ---- epilogue: out row = [q, A, q-A, q*A], q exact fp32 from global ----
    float* outb = out + ((size_t)dir * NB * SL + (size_t)bi * SL + i0) * 512;
    #pragma unroll
    for (int k = 0; k < 8; ++k) {
        int s = tid + 256 * k;          // 2048 slots: row (0..63), c4 (0..31)
        int r = s >> 5, c4 = s & 31;
        float4 a = *(const float4*)(aOut + r * 132 + c4 * 4);
        float4 q = *(const float4*)(xq + ((size_t)bi * SL + i0 + r) * 128 + c4 * 4);
        float4 d, m;
        d.x = q.x - a.x; d.y = q.y - a.y; d.z = q.z - a.z; d.w = q.w - a.w;
        m.x = q.x * a.x; m.y = q.y * a.y; m.z = q.z * a.z; m.w = q.w * a.w;
        float4* orow = (float4*)(outb + (size_t)r * 512);
        orow[c4]      = q;
        orow[32 + c4] = a;
        orow[64 + c4] = d;
        orow[96 + c4] = m;
    }
}

extern "C" void kernel_launch(void* const* d_in, const int* in_sizes, int n_in,
                              void* d_out, int out_size, void* d_ws, size_t ws_size,
                              hipStream_t stream) {
    const float* x1 = (const float*)d_in[0];
    const float* x2 = (const float*)d_in[1];
    float* out = (float*)d_out;
    (void)d_ws; (void)ws_size; (void)in_sizes; (void)n_in; (void)out_size;

    dim3 grid(SL / TI, NB, 2);
    dim3 block(256);
    soft_attn_align_mfma<<<grid, block, 0, stream>>>(x1, x2, out);
}

// Round 6
// 130.620 us; speedup vs baseline: 1.2694x; 1.2694x over previous
//
#include <hip/hip_runtime.h>

// SoftAttentionAlignment B=8, L=2048, D=128 fp32. MFMA flash attention, both dirs.
// R11: the R6..R10 invariant (104us) was TA/L1 address divergence: staging lanes
//      strode 512B -> 64 cache lines per wave-load, ~4096 line-transactions per
//      CU-tile. Fix at the source with a PREPASS kernel that writes f16 row-major
//      copies (K/Q) and bf16 TRANSPOSED [B][D][L] copies (V) into d_ws. Main-kernel
//      staging is now fully coalesced (16 lines/wave-load), half the bytes, zero
//      conversion VALU, and all-LDS-b128 with bank-uniform patterns (no swizzle
//      needed at V stride 64B: b128 cost = coverage uniformity, which holds).
//      Inner loop structure = R10 (harness-verified): 32 q-rows/wave, in-register
//      P via cvt_pk+permlane, async prefetch, 2 j-groups x 2 waves, TI=64.

typedef __bf16    bf16;
typedef _Float16  f16;
typedef __bf16    bf16x4 __attribute__((ext_vector_type(4)));
typedef _Float16  f16x4  __attribute__((ext_vector_type(4)));
typedef __bf16    bf16x8 __attribute__((ext_vector_type(8)));
typedef _Float16  f16x8  __attribute__((ext_vector_type(8)));
typedef float     floatx4 __attribute__((ext_vector_type(4)));
typedef unsigned int uintx4 __attribute__((ext_vector_type(4)));

#define NB 8
#define SL 2048
#define TI 64
#define NT 32            // 32 j-tiles of 32 per group (group owns 1024 j)

#define F16SZ (NB * SL * 128 * 2)   // 4,194,304 B per converted array

#define SKV_S  136   // f16 elems per j-row (272 B): uniform-start b128 banks
#define SVT_S  32    // bf16 elems per d-row (64 B): uniform-start b128 banks

// per-group LDS: sKV [32][136] f16 = 8704 B ; sVT [128][32] bf16 = 8192 B
#define OFF_VT   8704
#define GSPAN    16896
#define OFF_L    33792           // float[64]
#define LDS_BYTES 34048          // aOut fp32 [64][132] = 33792 overlaps group buffers

// ---------------- prepass: fp32 -> f16 (same layout) + bf16 transposed ----------
__global__ __launch_bounds__(256)
void prepass_cvt(const float* __restrict__ x1, const float* __restrict__ x2,
                 char* __restrict__ ws)
{
    __shared__ float tile[64 * 129];
    const int tid = threadIdx.x;
    const int j0  = blockIdx.x * 64;
    const int b   = blockIdx.y;
    const int z   = blockIdx.z;
    const float* src = z ? x2 : x1;
    f16*  oF = (f16*) (ws + (size_t)z * F16SZ);
    bf16* oT = (bf16*)(ws + 2 * (size_t)F16SZ + (size_t)z * F16SZ);

    #pragma unroll
    for (int n = 0; n < 8; ++n) {
        int ci = n * 256 + tid;              // 0..2047
        int row = ci >> 5, c4 = ci & 31;
        const float4 v = *(const float4*)(src + ((size_t)b * SL + j0 + row) * 128 + c4 * 4);
        tile[row * 129 + c4 * 4 + 0] = v.x;
        tile[row * 129 + c4 * 4 + 1] = v.y;
        tile[row * 129 + c4 * 4 + 2] = v.z;
        tile[row * 129 + c4 * 4 + 3] = v.w;
        f16x4 h; h[0] = (f16)v.x; h[1] = (f16)v.y; h[2] = (f16)v.z; h[3] = (f16)v.w;
        *(f16x4*)(oF + ((size_t)b * SL + j0 + row) * 128 + c4 * 4) = h;
    }
    __syncthreads();
    #pragma unroll
    for (int n = 0; n < 8; ++n) {
        int fi = n * 256 + tid;              // 0..2047
        int jg = fi & 15, d = fi >> 4;
        bf16x4 o;
        #pragma unroll
        for (int i = 0; i < 4; ++i) o[i] = (bf16)tile[(jg * 4 + i) * 129 + d];
        *(bf16x4*)(oT + ((size_t)b * 128 + d) * SL + j0 + jg * 4) = o;
    }
}

// ---------------- main kernel -----------------------------------------------
__global__ __launch_bounds__(256, 2)
void soft_attn_align_mfma(const float* __restrict__ x1,
                          const float* __restrict__ x2,
                          const char* __restrict__ ws,
                          float* __restrict__ out)
{
    __shared__ __align__(16) char lds_raw[LDS_BYTES];

    const int tid  = threadIdx.x;
    const int lane = tid & 63;
    const int wv   = tid >> 6;          // 0..3
    const int g    = wv >> 1;           // j-half group
    const int rowbase = (wv & 1) * 32;  // wave's 32 q-rows within the 64-row tile
    const int lr   = lane & 15;
    const int lq   = lane >> 4;
    const int t128 = tid & 127;         // thread id within group

    char* gb   = lds_raw + g * GSPAN;
    f16*   sKV  = (f16*) (gb);             // [32][136] fp16 row-major (j, d)
    bf16*  sVT  = (bf16*)(gb + OFF_VT);    // [128][32] bf16 d-major (d, j)
    float* aOut = (float*)(lds_raw);       // [64][132] fp32 (epilogue/combine)
    float* sL   = (float*)(lds_raw + OFF_L);

    const int i0  = blockIdx.x * TI;
    const int bi  = blockIdx.y;
    const int dir = blockIdx.z;

    const float* xq = dir ? x2 : x1;                     // epilogue (exact fp32)
    const f16*  x1f = (const f16*)(ws);
    const f16*  x2f = (const f16*)(ws + F16SZ);
    const bf16* x1T = (const bf16*)(ws + 2 * (size_t)F16SZ);
    const bf16* x2T = (const bf16*)(ws + 3 * (size_t)F16SZ);
    const f16*  xqf  = dir ? x2f : x1f;
    const f16*  xkvf = dir ? x1f : x2f;
    const bf16* xvT  = dir ? x1T : x2T;

    // ---- Q fragments (f16) straight from converted array ----
    f16x8 aQ[2][4];
    #pragma unroll
    for (int rb = 0; rb < 2; ++rb) {
        const f16* qrow = xqf + ((size_t)bi * SL + i0 + rowbase + rb * 16 + lr) * 128;
        #pragma unroll
        for (int kk = 0; kk < 4; ++kk)
            aQ[rb][kk] = *(const f16x8*)(qrow + kk * 32 + lq * 8);
    }

    float   l_acc[2] = {0.f, 0.f};
    floatx4 Oacc[2][8];
    #pragma unroll
    for (int rb = 0; rb < 2; ++rb)
        #pragma unroll
        for (int nd = 0; nd < 8; ++nd) Oacc[rb][nd] = (floatx4){0.f, 0.f, 0.f, 0.f};

    // staging assignment (coalesced): chunk n in 0..3, ci = n*128 + t128
    //   K: row = ci>>4 (j), col8 = ci&15 (8-f16 chunk)  -> 16B contiguous/lane
    //   V: d = ci>>2, jc = ci&3 (8-bf16 chunk)          -> 16B contiguous/lane
    const int rowK = t128 >> 4, colK = t128 & 15;
    const int dV0  = t128 >> 2, jcV  = t128 & 3;
    const f16*  kvf = xkvf + ((size_t)bi * SL + g * 1024 + rowK) * 128 + colK * 8;
    const bf16* vTf = xvT + ((size_t)bi * 128 + dV0) * SL + g * 1024 + jcV * 8;

    f16x8  kreg[4];
    bf16x8 vreg[4];
    {   // prologue: load tile 0 (chunk n advances row by 8 for K, d by 32 for V)
        #pragma unroll
        for (int n = 0; n < 4; ++n) {
            kreg[n] = *(const f16x8*)(kvf + (size_t)n * 8 * 128);
            vreg[n] = *(const bf16x8*)(vTf + (size_t)n * 32 * SL);
        }
    }

    for (int t = 0; t < NT; ++t) {
        __syncthreads();   // (A) prev tile's fragment reads done before restage

        // ---- write staged regs (tile t): 8 x ds_write_b128, bank-uniform ----
        #pragma unroll
        for (int n = 0; n < 4; ++n) {
            *(f16x8*) (sKV + (rowK + n * 8) * SKV_S + colK * 8) = kreg[n];
            *(bf16x8*)(sVT + (dV0 + n * 32) * SVT_S + jcV * 8)  = vreg[n];
        }
        __syncthreads();   // (B) tile t staged

        // ---- issue global loads for tile t+1 (land under the MFMA work) ----
        if (t < NT - 1) {
            const f16*  kb = kvf + (size_t)(t + 1) * 32 * 128;
            const bf16* vb = vTf + (size_t)(t + 1) * 32;
            #pragma unroll
            for (int n = 0; n < 4; ++n) {
                kreg[n] = *(const f16x8*)(kb + (size_t)n * 8 * 128);
                vreg[n] = *(const bf16x8*)(vb + (size_t)n * 32 * SL);
            }
        }

        // ---- S^T = K . Q^T : lane holds S[i=rowbase+16rb+lr][j = 16n+4lq+r] ----
        floatx4 Sf[2][2];
        Sf[0][0] = (floatx4){0.f,0.f,0.f,0.f}; Sf[0][1] = (floatx4){0.f,0.f,0.f,0.f};
        Sf[1][0] = (floatx4){0.f,0.f,0.f,0.f}; Sf[1][1] = (floatx4){0.f,0.f,0.f,0.f};
        __builtin_amdgcn_s_setprio(1);
        #pragma unroll
        for (int kk = 0; kk < 4; ++kk) {
            f16x8 aK0 = *(const f16x8*)(sKV + (lr)      * SKV_S + kk * 32 + lq * 8);
            f16x8 aK1 = *(const f16x8*)(sKV + (16 + lr) * SKV_S + kk * 32 + lq * 8);
            Sf[0][0] = __builtin_amdgcn_mfma_f32_16x16x32_f16(aK0, aQ[0][kk], Sf[0][0], 0, 0, 0);
            Sf[0][1] = __builtin_amdgcn_mfma_f32_16x16x32_f16(aK1, aQ[0][kk], Sf[0][1], 0, 0, 0);
            Sf[1][0] = __builtin_amdgcn_mfma_f32_16x16x32_f16(aK0, aQ[1][kk], Sf[1][0], 0, 0, 0);
            Sf[1][1] = __builtin_amdgcn_mfma_f32_16x16x32_f16(aK1, aQ[1][kk], Sf[1][1], 0, 0, 0);
        }
        __builtin_amdgcn_s_setprio(0);

        // ---- p = exp(S); pack bf16; permlane-redistribute into PV A-frags ----
        bf16x8 aP[2];
        #pragma unroll
        for (int rb = 0; rb < 2; ++rb) {
            float p00 = __expf(Sf[rb][0][0]), p01 = __expf(Sf[rb][0][1]);
            float p02 = __expf(Sf[rb][0][2]), p03 = __expf(Sf[rb][0][3]);
            float p10 = __expf(Sf[rb][1][0]), p11 = __expf(Sf[rb][1][1]);
            float p12 = __expf(Sf[rb][1][2]), p13 = __expf(Sf[rb][1][3]);
            l_acc[rb] += ((p00 + p01) + (p02 + p03)) + ((p10 + p11) + (p12 + p13));

            unsigned int A0, B0, A1, B1;
            asm("v_cvt_pk_bf16_f32 %0, %1, %2" : "=v"(A0) : "v"(p00), "v"(p01));
            asm("v_cvt_pk_bf16_f32 %0, %1, %2" : "=v"(B0) : "v"(p02), "v"(p03));
            asm("v_cvt_pk_bf16_f32 %0, %1, %2" : "=v"(A1) : "v"(p10), "v"(p11));
            asm("v_cvt_pk_bf16_f32 %0, %1, %2" : "=v"(B1) : "v"(p12), "v"(p13));
            asm("v_permlane32_swap_b32 %0, %1" : "+v"(A0), "+v"(A1));
            asm("v_permlane16_swap_b32 %0, %1" : "+v"(A0), "+v"(A1));  // A0=d0, A1=d2
            asm("v_permlane32_swap_b32 %0, %1" : "+v"(B0), "+v"(B1));
            asm("v_permlane16_swap_b32 %0, %1" : "+v"(B0), "+v"(B1));  // B0=d1, B1=d3
            uintx4 fr; fr.x = A0; fr.y = B0; fr.z = A1; fr.w = B1;
            aP[rb] = __builtin_bit_cast(bf16x8, fr);
        }

        // ---- O += P . V  (V fragment read once, shared across both rb) ----
        __builtin_amdgcn_s_setprio(1);
        #pragma unroll
        for (int nd = 0; nd < 8; ++nd) {
            bf16x8 bV = *(const bf16x8*)(sVT + (nd * 16 + lr) * SVT_S + lq * 8);
            Oacc[0][nd] = __builtin_amdgcn_mfma_f32_16x16x32_bf16(aP[0], bV, Oacc[0][nd], 0, 0, 0);
            Oacc[1][nd] = __builtin_amdgcn_mfma_f32_16x16x32_bf16(aP[1], bV, Oacc[1][nd], 0, 0, 0);
        }
        __builtin_amdgcn_s_setprio(0);
    }

    // ---- row sums: lane holds partial for i = rowbase+16rb+lr; reduce over lq ----
    float l_row[2][4];
    #pragma unroll
    for (int rb = 0; rb < 2; ++rb) {
        float lv = l_acc[rb];
        lv += __shfl_xor(lv, 16, 64);
        lv += __shfl_xor(lv, 32, 64);
        #pragma unroll
        for (int r = 0; r < 4; ++r)
            l_row[rb][r] = __shfl(lv, lq * 4 + r, 64);
    }

    __syncthreads();   // all tile-buffer reads done before combine overwrites LDS

    // ---- combine j-halves: group 1 publishes partials, group 0 merges ----
    if (g == 1) {
        #pragma unroll
        for (int rb = 0; rb < 2; ++rb)
            #pragma unroll
            for (int r = 0; r < 4; ++r) {
                int row = rowbase + rb * 16 + lq * 4 + r;
                #pragma unroll
                for (int nd = 0; nd < 8; ++nd)
                    aOut[row * 132 + nd * 16 + lr] = Oacc[rb][nd][r];
                if (lr == 0) sL[row] = l_row[rb][r];
            }
    }
    __syncthreads();
    if (g == 0) {
        #pragma unroll
        for (int rb = 0; rb < 2; ++rb)
            #pragma unroll
            for (int r = 0; r < 4; ++r) {
                int row = rowbase + rb * 16 + lq * 4 + r;
                float inv = 1.0f / (l_row[rb][r] + sL[row]);
                #pragma unroll
                for (int nd = 0; nd < 8; ++nd) {
                    int idx = row * 132 + nd * 16 + lr;
                    aOut[idx] = (Oacc[rb][nd][r] + aOut[idx]) * inv;
                }
            }
    }
    __syncthreads();

    // ---- epilogue: out row = [q, A, q-A, q*A], q exact fp32 from global ----
    float* outb = out + ((size_t)dir * NB * SL + (size_t)bi * SL + i0) * 512;
    #pragma unroll
    for (int k = 0; k < 8; ++k) {
        int s = tid + 256 * k;          // 2048 slots: row (0..63), c4 (0..31)
        int r = s >> 5, c4 = s & 31;
        float4 a = *(const float4*)(aOut + r * 132 + c4 * 4);
        float4 q = *(const float4*)(xq + ((size_t)bi * SL + i0 + r) * 128 + c4 * 4);
        float4 d, m;
        d.x = q.x - a.x; d.y = q.y - a.y; d.z = q.z - a.z; d.w = q.w - a.w;
        m.x = q.x * a.x; m.y = q.y * a.y; m.z = q.z * a.z; m.w = q.w * a.w;
        float4* orow = (float4*)(outb + (size_t)r * 512);
        orow[c4]      = q;
        orow[32 + c4] = a;
        orow[64 + c4] = d;
        orow[96 + c4] = m;
    }
}

extern "C" void kernel_launch(void* const* d_in, const int* in_sizes, int n_in,
                              void* d_out, int out_size, void* d_ws, size_t ws_size,
                              hipStream_t stream) {
    const float* x1 = (const float*)d_in[0];
    const float* x2 = (const float*)d_in[1];
    float* out = (float*)d_out;
    (void)in_sizes; (void)n_in; (void)out_size; (void)ws_size;

    dim3 pgrid(SL / 64, NB, 2);
    prepass_cvt<<<pgrid, dim3(256), 0, stream>>>(x1, x2, (char*)d_ws);

    dim3 grid(SL / TI, NB, 2);
    soft_attn_align_mfma<<<grid, dim3(256), 0, stream>>>(x1, x2, (const char*)d_ws, out);
}